// Round 1
// baseline (332.662 us; speedup 1.0000x reference)
//
#include <hip/hip_runtime.h>
#include <hip/hip_bf16.h>

// LinearAttention: B=8, C=512, L=4096, HEADS=8, dim_head=64, hidden=512
// Pipeline:
//   1. cvt w_qkv -> bf16                       [o][c] (A operand, k-contig)
//   2. transpose+cvt x -> x_t bf16             [b][l][c] (Bt operand)
//   3. zero ctx accumulator
//   4. GEMM1: qkv = w_qkv @ x  (M=1536,N=4096,K=512/batch) -> q bf16, k fp32, v bf16
//   5. softmax over k rows -> k_s bf16
//   6. transpose q -> q_t bf16                 [b][l][c'] (Bt operand)  (aliases k region)
//   7. ctx[b,h,d,e] = sum_n k_s[d,n] v[e,n]   (split-K, fp32 atomics)
//   8. w2[b][o][h*64+d] = sum_e w_out[o][h*64+e] * ctx[b,h,d,e]  -> bf16
//   9. GEMM2: out = w2 @ q + b_out  (M=512,N=4096,K=512/batch) -> fp32

typedef __bf16 bf16x8 __attribute__((ext_vector_type(8)));
typedef float  f32x4  __attribute__((ext_vector_type(4)));

#define B_  8
#define L_  4096
#define C_  512

// ---------------- small elementwise convert ----------------
__global__ void cvt_bf16(const float* __restrict__ in, __hip_bfloat16* __restrict__ out, int n) {
    int i = blockIdx.x * 256 + threadIdx.x;
    if (i < n) out[i] = __float2bfloat16(in[i]);
}

__global__ void zero_f4(float4* p, int n4) {
    int i = blockIdx.x * 256 + threadIdx.x;
    if (i < n4) p[i] = make_float4(0.f, 0.f, 0.f, 0.f);
}

// ---------------- transpose fp32 [b][C][L] -> bf16 [b][L][C] ----------------
__global__ __launch_bounds__(256) void transpose_cvt(const float* __restrict__ x,
                                                     __hip_bfloat16* __restrict__ xt) {
    __shared__ float tile[32][33];
    int b = blockIdx.z;
    int l0 = blockIdx.x * 32, c0 = blockIdx.y * 32;
    int tx = threadIdx.x & 31, ty = threadIdx.x >> 5;  // ty 0..7
    const float* xp = x + ((size_t)b * C_ + c0) * L_ + l0;
    for (int r = 0; r < 32; r += 8)
        tile[ty + r][tx] = xp[(size_t)(ty + r) * L_ + tx];
    __syncthreads();
    __hip_bfloat16* xo = xt + ((size_t)b * L_ + l0) * C_ + c0;
    for (int r = 0; r < 32; r += 8)
        xo[(size_t)(ty + r) * C_ + tx] = __float2bfloat16(tile[tx][ty + r]);
}

// ---------------- transpose bf16 [b][C][L] -> bf16 [b][L][C] ----------------
__global__ __launch_bounds__(256) void transpose_bf(const __hip_bfloat16* __restrict__ in,
                                                    __hip_bfloat16* __restrict__ outp) {
    __shared__ unsigned short tile[32][33];
    int b = blockIdx.z;
    int l0 = blockIdx.x * 32, c0 = blockIdx.y * 32;
    int tx = threadIdx.x & 31, ty = threadIdx.x >> 5;
    const unsigned short* ip = (const unsigned short*)in + ((size_t)b * C_ + c0) * L_ + l0;
    for (int r = 0; r < 32; r += 8)
        tile[ty + r][tx] = ip[(size_t)(ty + r) * L_ + tx];
    __syncthreads();
    unsigned short* op = (unsigned short*)outp + ((size_t)b * L_ + l0) * C_ + c0;
    for (int r = 0; r < 32; r += 8)
        op[(size_t)(ty + r) * C_ + tx] = tile[tx][ty + r];
}

// ---------------- main GEMM: C[M][N] = A[M][K] * Bt[N][K]^T ----------------
// A row-major [M][K], Bt row-major [N][K], both bf16, K%32==0, M%128==0, N%128==0.
// MODE 1: split rows into q (bf16) / k (fp32) / v (bf16), each [b][512][N]
// MODE 2: out fp32 [b][M][N] with bias[M]
template <int MODE>
__global__ __launch_bounds__(256) void gemm_bt(
    const __hip_bfloat16* __restrict__ A, const __hip_bfloat16* __restrict__ Bt,
    size_t strideA, size_t strideB, int M, int N, int K,
    __hip_bfloat16* __restrict__ qb, float* __restrict__ kb, __hip_bfloat16* __restrict__ vb,
    float* __restrict__ outb, const float* __restrict__ bias) {
    __shared__ alignas(16) unsigned short As[128 * 40];  // row stride 40 el = 80 B (16B-aligned, 2-way banks)
    __shared__ alignas(16) unsigned short Bs[128 * 40];

    int b = blockIdx.z;
    int m0 = blockIdx.y * 128, n0 = blockIdx.x * 128;
    const __hip_bfloat16* Ab = A + strideA * (size_t)b;
    const __hip_bfloat16* Bb = Bt + strideB * (size_t)b;

    int t = threadIdx.x;
    int lane = t & 63, wv = t >> 6;
    int l16 = lane & 15, q4 = lane >> 4;
    int wr = (wv >> 1) * 64, wc = (wv & 1) * 64;  // wave quadrant of 128x128
    int sr = t >> 2;           // staging row 0..63
    int sc = (t & 3) * 8;      // staging col 0,8,16,24

    f32x4 acc[4][4] = {};

    for (int k0 = 0; k0 < K; k0 += 32) {
        uint4 a0 = *(const uint4*)(Ab + (size_t)(m0 + sr) * K + k0 + sc);
        uint4 a1 = *(const uint4*)(Ab + (size_t)(m0 + 64 + sr) * K + k0 + sc);
        uint4 b0 = *(const uint4*)(Bb + (size_t)(n0 + sr) * K + k0 + sc);
        uint4 b1 = *(const uint4*)(Bb + (size_t)(n0 + 64 + sr) * K + k0 + sc);
        __syncthreads();  // previous iter's LDS reads done
        *(uint4*)&As[sr * 40 + sc] = a0;
        *(uint4*)&As[(64 + sr) * 40 + sc] = a1;
        *(uint4*)&Bs[sr * 40 + sc] = b0;
        *(uint4*)&Bs[(64 + sr) * 40 + sc] = b1;
        __syncthreads();

        bf16x8 af[4], bfr[4];
#pragma unroll
        for (int i = 0; i < 4; i++) {
            af[i]  = *(const bf16x8*)&As[(wr + i * 16 + l16) * 40 + q4 * 8];
            bfr[i] = *(const bf16x8*)&Bs[(wc + i * 16 + l16) * 40 + q4 * 8];
        }
#pragma unroll
        for (int i = 0; i < 4; i++)
#pragma unroll
            for (int j = 0; j < 4; j++)
                acc[i][j] = __builtin_amdgcn_mfma_f32_16x16x32_bf16(af[i], bfr[j], acc[i][j], 0, 0, 0);
    }

    // epilogue: D row = quad*4 + reg, col = lane&15  (m89-verified C/D layout)
#pragma unroll
    for (int i = 0; i < 4; i++)
#pragma unroll
        for (int j = 0; j < 4; j++)
#pragma unroll
            for (int r = 0; r < 4; r++) {
                int row = m0 + wr + i * 16 + q4 * 4 + r;
                int col = n0 + wc + j * 16 + l16;
                float val = acc[i][j][r];
                if (MODE == 1) {
                    int part = row >> 9, od = row & 511;  // block-uniform part
                    size_t idx = ((size_t)b * 512 + od) * (size_t)N + col;
                    if (part == 0)      qb[idx] = __float2bfloat16(val);
                    else if (part == 1) kb[idx] = val;
                    else                vb[idx] = __float2bfloat16(val);
                } else {
                    outb[((size_t)b * 512 + row) * (size_t)N + col] = val + bias[row];
                }
            }
}

// ---------------- softmax over rows of k (fp32 in, bf16 out) ----------------
__global__ __launch_bounds__(256) void softmax_k(const float* __restrict__ kin,
                                                 __hip_bfloat16* __restrict__ ks) {
    int row = blockIdx.x;  // 0..4095 = b*512 + h*64 + d
    const float* kp = kin + (size_t)row * L_;
    __shared__ float buf[L_];
    __shared__ float red[8];
    int t = threadIdx.x, lane = t & 63, wv = t >> 6;
    float m = -1e30f;
    for (int i = t; i < L_; i += 256) { float x = kp[i]; buf[i] = x; m = fmaxf(m, x); }
    for (int o = 32; o; o >>= 1) m = fmaxf(m, __shfl_xor(m, o, 64));
    if (lane == 0) red[wv] = m;
    __syncthreads();
    m = fmaxf(fmaxf(red[0], red[1]), fmaxf(red[2], red[3]));
    float s = 0.f;
    for (int i = t; i < L_; i += 256) { float e = __expf(buf[i] - m); buf[i] = e; s += e; }
    for (int o = 32; o; o >>= 1) s += __shfl_xor(s, o, 64);
    if (lane == 0) red[4 + wv] = s;
    __syncthreads();
    s = red[4] + red[5] + red[6] + red[7];
    float inv = 1.0f / s;
    __hip_bfloat16* op = ks + (size_t)row * L_;
    for (int i = t; i < L_; i += 256) op[i] = __float2bfloat16(buf[i] * inv);
}

// ---------------- ctx[b,h,d,e] = sum_n k_s[b,h,d,n]*v[b,h,e,n], split-K x8 ----------------
__global__ __launch_bounds__(256) void ctx_kernel(const __hip_bfloat16* __restrict__ ks,
                                                  const __hip_bfloat16* __restrict__ v,
                                                  float* __restrict__ ctx) {
    int kc = blockIdx.x, h = blockIdx.y, b = blockIdx.z;
    int t = threadIdx.x, lane = t & 63, wv = t >> 6;
    int l16 = lane & 15, q4 = lane >> 4;
    const __hip_bfloat16* ka = ks + ((size_t)b * 512 + h * 64) * L_;
    const __hip_bfloat16* va = v + ((size_t)b * 512 + h * 64) * L_;
    f32x4 acc[4][4] = {};
    int nbase = kc * 512 + wv * 128;
#pragma unroll
    for (int s = 0; s < 4; s++) {
        int n = nbase + s * 32 + q4 * 8;
        bf16x8 af[4], bfr[4];
#pragma unroll
        for (int i = 0; i < 4; i++) {
            af[i]  = *(const bf16x8*)(ka + (size_t)(i * 16 + l16) * L_ + n);
            bfr[i] = *(const bf16x8*)(va + (size_t)(i * 16 + l16) * L_ + n);
        }
#pragma unroll
        for (int i = 0; i < 4; i++)
#pragma unroll
            for (int j = 0; j < 4; j++)
                acc[i][j] = __builtin_amdgcn_mfma_f32_16x16x32_bf16(af[i], bfr[j], acc[i][j], 0, 0, 0);
    }
    __shared__ float cbuf[4096];
    for (int w = 0; w < 4; w++) {
        if (wv == w) {
#pragma unroll
            for (int i = 0; i < 4; i++)
#pragma unroll
                for (int j = 0; j < 4; j++)
#pragma unroll
                    for (int r = 0; r < 4; r++) {
                        int mm = i * 16 + q4 * 4 + r, nn = j * 16 + l16;
                        float pv = acc[i][j][r];
                        if (w == 0) cbuf[mm * 64 + nn] = pv;
                        else        cbuf[mm * 64 + nn] += pv;
                    }
        }
        __syncthreads();
    }
    float* cg = ctx + ((size_t)b * 8 + h) * 4096;
    for (int i = t; i < 4096; i += 256) atomicAdd(&cg[i], cbuf[i]);
}

// ---------------- w2[b][o][h*64+d] = sum_e w_out[o][h*64+e]*ctx[b,h,d,e] ----------------
__global__ __launch_bounds__(256) void w2_kernel(const float* __restrict__ wout,
                                                 const float* __restrict__ ctx,
                                                 __hip_bfloat16* __restrict__ w2) {
    int ob = blockIdx.x, h = blockIdx.y, b = blockIdx.z;
    __shared__ float cT[64 * 65];  // [e][d]
    __shared__ float wT[64 * 65];  // [e][ol]
    int t = threadIdx.x;
    const float* cg = ctx + ((size_t)b * 8 + h) * 4096;
    for (int i = t; i < 4096; i += 256) {
        int d = i >> 6, e = i & 63;
        cT[e * 65 + d] = cg[i];                                     // read coalesced, write stride-65
        wT[e * 65 + d] = wout[(size_t)(ob * 64 + d) * 512 + h * 64 + e];  // d plays 'ol' here
    }
    __syncthreads();
    int ol = t >> 2;
    int db = (t & 3) * 16;
    for (int dd = 0; dd < 16; dd++) {
        int d = db + dd;
        float s = 0.f;
#pragma unroll
        for (int e = 0; e < 64; e++) s += wT[e * 65 + ol] * cT[e * 65 + d];
        w2[((size_t)b * 512 + ob * 64 + ol) * 512 + h * 64 + d] = __float2bfloat16(s);
    }
}

// ---------------- launch ----------------
extern "C" void kernel_launch(void* const* d_in, const int* in_sizes, int n_in,
                              void* d_out, int out_size, void* d_ws, size_t ws_size,
                              hipStream_t stream) {
    const float* x     = (const float*)d_in[0];
    const float* w_qkv = (const float*)d_in[1];
    const float* w_out = (const float*)d_in[2];
    const float* b_out = (const float*)d_in[3];
    float* out = (float*)d_out;
    char* ws = (char*)d_ws;

    const size_t QKV = (size_t)B_ * 512 * L_;  // elements per q/k/v tensor
    size_t off_xt  = 0;                              // bf16 [b][L][C]     32 MiB
    size_t off_wq  = off_xt + (size_t)B_ * L_ * C_ * 2;  // bf16 1536x512   1.5 MiB
    size_t off_q   = off_wq + (size_t)1536 * 512 * 2;    // bf16            32 MiB
    size_t off_k   = off_q + QKV * 2;                    // fp32            64 MiB
    size_t off_ks  = off_k + QKV * 4;                    // bf16            32 MiB
    size_t off_v   = off_ks + QKV * 2;                   // bf16            32 MiB
    size_t off_ctx = off_v + QKV * 2;                    // fp32 8*8*64*64   1 MiB
    size_t off_w2  = off_ctx + (size_t)B_ * 8 * 64 * 64 * 4;  // bf16 8*512*512  4 MiB
    size_t off_qt  = off_k;  // alias: q_t reuses k region (k dead after softmax)

    __hip_bfloat16* xt = (__hip_bfloat16*)(ws + off_xt);
    __hip_bfloat16* wq = (__hip_bfloat16*)(ws + off_wq);
    __hip_bfloat16* qb = (__hip_bfloat16*)(ws + off_q);
    float*          kb = (float*)(ws + off_k);
    __hip_bfloat16* ksb = (__hip_bfloat16*)(ws + off_ks);
    __hip_bfloat16* vb = (__hip_bfloat16*)(ws + off_v);
    float*          ctx = (float*)(ws + off_ctx);
    __hip_bfloat16* w2 = (__hip_bfloat16*)(ws + off_w2);
    __hip_bfloat16* qt = (__hip_bfloat16*)(ws + off_qt);

    cvt_bf16<<<(1536 * 512 + 255) / 256, 256, 0, stream>>>(w_qkv, wq, 1536 * 512);
    transpose_cvt<<<dim3(L_ / 32, C_ / 32, B_), 256, 0, stream>>>(x, xt);
    zero_f4<<<(B_ * 8 * 64 * 64 / 4 + 255) / 256, 256, 0, stream>>>((float4*)ctx, B_ * 8 * 64 * 64 / 4);

    gemm_bt<1><<<dim3(L_ / 128, 1536 / 128, B_), 256, 0, stream>>>(
        wq, xt, 0, (size_t)L_ * C_, 1536, L_, 512, qb, kb, vb, nullptr, nullptr);

    softmax_k<<<B_ * 512, 256, 0, stream>>>(kb, ksb);
    transpose_bf<<<dim3(L_ / 32, C_ / 32, B_), 256, 0, stream>>>(qb, qt);
    ctx_kernel<<<dim3(8, 8, B_), 256, 0, stream>>>(ksb, vb, ctx);
    w2_kernel<<<dim3(8, 8, B_), 256, 0, stream>>>(w_out, ctx, w2);

    gemm_bt<2><<<dim3(L_ / 128, 512 / 128, B_), 256, 0, stream>>>(
        w2, qt, (size_t)512 * 512, (size_t)L_ * C_, 512, L_, 512, nullptr, nullptr, nullptr, out, b_out);
}

// Round 2
// 316.006 us; speedup vs baseline: 1.0527x; 1.0527x over previous
//
#include <hip/hip_runtime.h>
#include <hip/hip_bf16.h>

// LinearAttention: B=8, C=512, L=4096, HEADS=8, dim_head=64, hidden=512
// R2: gemm_bt upgraded to global_load_lds(16B) staging with XOR-swizzled LDS
//     (m97 rung, 874 TF); k stored bf16 (saves 32MiB write + 32MiB read);
//     softmax vectorized bf16x8.

typedef __bf16 bf16x8 __attribute__((ext_vector_type(8)));
typedef float  f32x4  __attribute__((ext_vector_type(4)));

#define B_  8
#define L_  4096
#define C_  512

#define GLD_LDS16(g, l)                                             \
    __builtin_amdgcn_global_load_lds(                               \
        (const __attribute__((address_space(1))) void*)(g),         \
        (__attribute__((address_space(3))) void*)(l), 16, 0, 0)

// ---------------- small elementwise convert ----------------
__global__ void cvt_bf16(const float* __restrict__ in, __hip_bfloat16* __restrict__ out, int n) {
    int i = blockIdx.x * 256 + threadIdx.x;
    if (i < n) out[i] = __float2bfloat16(in[i]);
}

__global__ void zero_f4(float4* p, int n4) {
    int i = blockIdx.x * 256 + threadIdx.x;
    if (i < n4) p[i] = make_float4(0.f, 0.f, 0.f, 0.f);
}

// ---------------- transpose fp32 [b][C][L] -> bf16 [b][L][C] ----------------
__global__ __launch_bounds__(256) void transpose_cvt(const float* __restrict__ x,
                                                     __hip_bfloat16* __restrict__ xt) {
    __shared__ float tile[32][33];
    int b = blockIdx.z;
    int l0 = blockIdx.x * 32, c0 = blockIdx.y * 32;
    int tx = threadIdx.x & 31, ty = threadIdx.x >> 5;  // ty 0..7
    const float* xp = x + ((size_t)b * C_ + c0) * L_ + l0;
    for (int r = 0; r < 32; r += 8)
        tile[ty + r][tx] = xp[(size_t)(ty + r) * L_ + tx];
    __syncthreads();
    __hip_bfloat16* xo = xt + ((size_t)b * L_ + l0) * C_ + c0;
    for (int r = 0; r < 32; r += 8)
        xo[(size_t)(ty + r) * C_ + tx] = __float2bfloat16(tile[tx][ty + r]);
}

// ---------------- transpose bf16 [b][C][L] -> bf16 [b][L][C] ----------------
__global__ __launch_bounds__(256) void transpose_bf(const __hip_bfloat16* __restrict__ in,
                                                    __hip_bfloat16* __restrict__ outp) {
    __shared__ unsigned short tile[32][33];
    int b = blockIdx.z;
    int l0 = blockIdx.x * 32, c0 = blockIdx.y * 32;
    int tx = threadIdx.x & 31, ty = threadIdx.x >> 5;
    const unsigned short* ip = (const unsigned short*)in + ((size_t)b * C_ + c0) * L_ + l0;
    for (int r = 0; r < 32; r += 8)
        tile[ty + r][tx] = ip[(size_t)(ty + r) * L_ + tx];
    __syncthreads();
    unsigned short* op = (unsigned short*)outp + ((size_t)b * L_ + l0) * C_ + c0;
    for (int r = 0; r < 32; r += 8)
        op[(size_t)(ty + r) * C_ + tx] = tile[tx][ty + r];
}

// ---------------- main GEMM: C[M][N] = A[M][K] * Bt[N][K]^T ----------------
// A row-major [M][K], Bt row-major [N][K], both bf16, K%32==0, M%128==0, N%128==0.
// Staging: global_load_lds 16B/lane, LDS rows = 64B (32 bf16), 16B-groups
// XOR-swizzled by (row&3) so ds_read_b128 fragments alias only 2-way.
// MODE 1: split rows into q / k / v bf16, each [b][512][N]
// MODE 2: out fp32 [b][M][N] with bias[M]
template <int MODE>
__global__ __launch_bounds__(256) void gemm_bt(
    const __hip_bfloat16* __restrict__ A, const __hip_bfloat16* __restrict__ Bt,
    size_t strideA, size_t strideB, int M, int N, int K,
    __hip_bfloat16* __restrict__ qb, __hip_bfloat16* __restrict__ kb,
    __hip_bfloat16* __restrict__ vb,
    float* __restrict__ outb, const float* __restrict__ bias) {
    __shared__ alignas(16) unsigned short As[128 * 32];  // 8 KiB, rows 64B, swizzled
    __shared__ alignas(16) unsigned short Bs[128 * 32];

    int b = blockIdx.z;
    int m0 = blockIdx.y * 128, n0 = blockIdx.x * 128;
    const __hip_bfloat16* Ab = A + strideA * (size_t)b;
    const __hip_bfloat16* Bb = Bt + strideB * (size_t)b;

    int t = threadIdx.x;
    int lane = t & 63, wv = t >> 6;
    int l16 = lane & 15, q4 = lane >> 4;
    int wr = (wv >> 1) * 64, wc = (wv & 1) * 64;  // wave quadrant of 128x128

    // staging lane mapping: 16 rows/chunk, lane -> (row = lane>>2, kgroup = lane&3)
    int srow = lane >> 2;
    int skg  = lane & 3;
    int kc   = ((skg ^ (srow & 3)) * 8);  // swizzled k-column (elements)

    const __hip_bfloat16* gA0 = Ab + (size_t)(m0 + wv * 32 + srow) * K + kc;
    const __hip_bfloat16* gA1 = gA0 + (size_t)16 * K;
    const __hip_bfloat16* gB0 = Bb + (size_t)(n0 + wv * 32 + srow) * K + kc;
    const __hip_bfloat16* gB1 = gB0 + (size_t)16 * K;
    unsigned short* lA0 = &As[(wv * 32) * 32];
    unsigned short* lA1 = &As[(wv * 32 + 16) * 32];
    unsigned short* lB0 = &Bs[(wv * 32) * 32];
    unsigned short* lB1 = &Bs[(wv * 32 + 16) * 32];

    // fragment read addresses (swizzle: row&3 == l16&3)
    int fsw = (q4 ^ (l16 & 3)) * 8;

    f32x4 acc[4][4] = {};

    for (int k0 = 0; k0 < K; k0 += 32) {
        __syncthreads();  // previous iter's ds_reads done before overwrite
        GLD_LDS16(gA0 + k0, lA0);
        GLD_LDS16(gA1 + k0, lA1);
        GLD_LDS16(gB0 + k0, lB0);
        GLD_LDS16(gB1 + k0, lB1);
        __syncthreads();  // vmcnt drained + all waves' data visible

        bf16x8 af[4], bfr[4];
#pragma unroll
        for (int i = 0; i < 4; i++) {
            af[i]  = *(const bf16x8*)&As[(wr + i * 16 + l16) * 32 + fsw];
            bfr[i] = *(const bf16x8*)&Bs[(wc + i * 16 + l16) * 32 + fsw];
        }
#pragma unroll
        for (int i = 0; i < 4; i++)
#pragma unroll
            for (int j = 0; j < 4; j++)
                acc[i][j] = __builtin_amdgcn_mfma_f32_16x16x32_bf16(af[i], bfr[j], acc[i][j], 0, 0, 0);
    }

    // epilogue: D row = quad*4 + reg, col = lane&15  (m89-verified C/D layout)
#pragma unroll
    for (int i = 0; i < 4; i++)
#pragma unroll
        for (int j = 0; j < 4; j++)
#pragma unroll
            for (int r = 0; r < 4; r++) {
                int row = m0 + wr + i * 16 + q4 * 4 + r;
                int col = n0 + wc + j * 16 + l16;
                float val = acc[i][j][r];
                if (MODE == 1) {
                    int part = row >> 9, od = row & 511;  // block-uniform part
                    size_t idx = ((size_t)b * 512 + od) * (size_t)N + col;
                    __hip_bfloat16 cv = __float2bfloat16(val);
                    if (part == 0)      qb[idx] = cv;
                    else if (part == 1) kb[idx] = cv;
                    else                vb[idx] = cv;
                } else {
                    outb[((size_t)b * 512 + row) * (size_t)N + col] = val + bias[row];
                }
            }
}

// ---------------- softmax over rows of k (bf16 in, bf16 out) ----------------
__global__ __launch_bounds__(256) void softmax_k(const __hip_bfloat16* __restrict__ kin,
                                                 __hip_bfloat16* __restrict__ ks) {
    int row = blockIdx.x;  // 0..4095 = b*512 + h*64 + d
    const unsigned short* kp = (const unsigned short*)kin + (size_t)row * L_;
    __shared__ float buf[L_];
    __shared__ float red[8];
    int t = threadIdx.x, lane = t & 63, wv = t >> 6;
    float m = -1e30f;
    for (int i0 = t * 8; i0 < L_; i0 += 256 * 8) {
        bf16x8 kv = *(const bf16x8*)(kp + i0);
#pragma unroll
        for (int j = 0; j < 8; j++) {
            float x = (float)kv[j];
            buf[i0 + j] = x;
            m = fmaxf(m, x);
        }
    }
    for (int o = 32; o; o >>= 1) m = fmaxf(m, __shfl_xor(m, o, 64));
    if (lane == 0) red[wv] = m;
    __syncthreads();
    m = fmaxf(fmaxf(red[0], red[1]), fmaxf(red[2], red[3]));
    float s = 0.f;
    for (int i = t; i < L_; i += 256) { float e = __expf(buf[i] - m); buf[i] = e; s += e; }
    for (int o = 32; o; o >>= 1) s += __shfl_xor(s, o, 64);
    if (lane == 0) red[4 + wv] = s;
    __syncthreads();
    s = red[4] + red[5] + red[6] + red[7];
    float inv = 1.0f / s;
    unsigned short* op = (unsigned short*)ks + (size_t)row * L_;
    for (int i0 = t * 8; i0 < L_; i0 += 256 * 8) {
        bf16x8 ov;
#pragma unroll
        for (int j = 0; j < 8; j++) ov[j] = (__bf16)(buf[i0 + j] * inv);
        *(bf16x8*)(op + i0) = ov;
    }
}

// ---------------- ctx[b,h,d,e] = sum_n k_s[b,h,d,n]*v[b,h,e,n], split-K x8 ----------------
__global__ __launch_bounds__(256) void ctx_kernel(const __hip_bfloat16* __restrict__ ks,
                                                  const __hip_bfloat16* __restrict__ v,
                                                  float* __restrict__ ctx) {
    int kc = blockIdx.x, h = blockIdx.y, b = blockIdx.z;
    int t = threadIdx.x, lane = t & 63, wv = t >> 6;
    int l16 = lane & 15, q4 = lane >> 4;
    const __hip_bfloat16* ka = ks + ((size_t)b * 512 + h * 64) * L_;
    const __hip_bfloat16* va = v + ((size_t)b * 512 + h * 64) * L_;
    f32x4 acc[4][4] = {};
    int nbase = kc * 512 + wv * 128;
#pragma unroll
    for (int s = 0; s < 4; s++) {
        int n = nbase + s * 32 + q4 * 8;
        bf16x8 af[4], bfr[4];
#pragma unroll
        for (int i = 0; i < 4; i++) {
            af[i]  = *(const bf16x8*)(ka + (size_t)(i * 16 + l16) * L_ + n);
            bfr[i] = *(const bf16x8*)(va + (size_t)(i * 16 + l16) * L_ + n);
        }
#pragma unroll
        for (int i = 0; i < 4; i++)
#pragma unroll
            for (int j = 0; j < 4; j++)
                acc[i][j] = __builtin_amdgcn_mfma_f32_16x16x32_bf16(af[i], bfr[j], acc[i][j], 0, 0, 0);
    }
    __shared__ float cbuf[4096];
    for (int w = 0; w < 4; w++) {
        if (wv == w) {
#pragma unroll
            for (int i = 0; i < 4; i++)
#pragma unroll
                for (int j = 0; j < 4; j++)
#pragma unroll
                    for (int r = 0; r < 4; r++) {
                        int mm = i * 16 + q4 * 4 + r, nn = j * 16 + l16;
                        float pv = acc[i][j][r];
                        if (w == 0) cbuf[mm * 64 + nn] = pv;
                        else        cbuf[mm * 64 + nn] += pv;
                    }
        }
        __syncthreads();
    }
    float* cg = ctx + ((size_t)b * 8 + h) * 4096;
    for (int i = t; i < 4096; i += 256) atomicAdd(&cg[i], cbuf[i]);
}

// ---------------- w2[b][o][h*64+d] = sum_e w_out[o][h*64+e]*ctx[b,h,d,e] ----------------
__global__ __launch_bounds__(256) void w2_kernel(const float* __restrict__ wout,
                                                 const float* __restrict__ ctx,
                                                 __hip_bfloat16* __restrict__ w2) {
    int ob = blockIdx.x, h = blockIdx.y, b = blockIdx.z;
    __shared__ float cT[64 * 65];  // [e][d]
    __shared__ float wT[64 * 65];  // [e][ol]
    int t = threadIdx.x;
    const float* cg = ctx + ((size_t)b * 8 + h) * 4096;
    for (int i = t; i < 4096; i += 256) {
        int d = i >> 6, e = i & 63;
        cT[e * 65 + d] = cg[i];
        wT[e * 65 + d] = wout[(size_t)(ob * 64 + d) * 512 + h * 64 + e];
    }
    __syncthreads();
    int ol = t >> 2;
    int db = (t & 3) * 16;
    for (int dd = 0; dd < 16; dd++) {
        int d = db + dd;
        float s = 0.f;
#pragma unroll
        for (int e = 0; e < 64; e++) s += wT[e * 65 + ol] * cT[e * 65 + d];
        w2[((size_t)b * 512 + ob * 64 + ol) * 512 + h * 64 + d] = __float2bfloat16(s);
    }
}

// ---------------- launch ----------------
extern "C" void kernel_launch(void* const* d_in, const int* in_sizes, int n_in,
                              void* d_out, int out_size, void* d_ws, size_t ws_size,
                              hipStream_t stream) {
    const float* x     = (const float*)d_in[0];
    const float* w_qkv = (const float*)d_in[1];
    const float* w_out = (const float*)d_in[2];
    const float* b_out = (const float*)d_in[3];
    float* out = (float*)d_out;
    char* ws = (char*)d_ws;

    const size_t QKV = (size_t)B_ * 512 * L_;  // elements per q/k/v tensor
    size_t off_xt  = 0;                                  // bf16 [b][L][C]   32 MiB
    size_t off_wq  = off_xt + (size_t)B_ * L_ * C_ * 2;  // bf16 1536x512   1.5 MiB
    size_t off_q   = off_wq + (size_t)1536 * 512 * 2;    // bf16            32 MiB
    size_t off_k   = off_q + QKV * 2;                    // bf16            32 MiB
    size_t off_ks  = off_k + QKV * 2;                    // bf16            32 MiB
    size_t off_v   = off_ks + QKV * 2;                   // bf16            32 MiB
    size_t off_ctx = off_v + QKV * 2;                    // fp32 8*8*64*64   1 MiB
    size_t off_w2  = off_ctx + (size_t)B_ * 8 * 64 * 64 * 4;  // bf16 8*512*512  4 MiB
    size_t off_qt  = off_k;  // alias: q_t reuses k region (k dead after softmax)

    __hip_bfloat16* xt  = (__hip_bfloat16*)(ws + off_xt);
    __hip_bfloat16* wq  = (__hip_bfloat16*)(ws + off_wq);
    __hip_bfloat16* qb  = (__hip_bfloat16*)(ws + off_q);
    __hip_bfloat16* kb  = (__hip_bfloat16*)(ws + off_k);
    __hip_bfloat16* ksb = (__hip_bfloat16*)(ws + off_ks);
    __hip_bfloat16* vb  = (__hip_bfloat16*)(ws + off_v);
    float*          ctx = (float*)(ws + off_ctx);
    __hip_bfloat16* w2  = (__hip_bfloat16*)(ws + off_w2);
    __hip_bfloat16* qt  = (__hip_bfloat16*)(ws + off_qt);

    cvt_bf16<<<(1536 * 512 + 255) / 256, 256, 0, stream>>>(w_qkv, wq, 1536 * 512);
    transpose_cvt<<<dim3(L_ / 32, C_ / 32, B_), 256, 0, stream>>>(x, xt);
    zero_f4<<<(B_ * 8 * 64 * 64 / 4 + 255) / 256, 256, 0, stream>>>((float4*)ctx, B_ * 8 * 64 * 64 / 4);

    gemm_bt<1><<<dim3(L_ / 128, 1536 / 128, B_), 256, 0, stream>>>(
        wq, xt, 0, (size_t)L_ * C_, 1536, L_, 512, qb, kb, vb, nullptr, nullptr);

    softmax_k<<<B_ * 512, 256, 0, stream>>>(kb, ksb);
    transpose_bf<<<dim3(L_ / 32, C_ / 32, B_), 256, 0, stream>>>(qb, qt);
    ctx_kernel<<<dim3(8, 8, B_), 256, 0, stream>>>(ksb, vb, ctx);
    w2_kernel<<<dim3(8, 8, B_), 256, 0, stream>>>(w_out, ctx, w2);

    gemm_bt<2><<<dim3(L_ / 128, 512 / 128, B_), 256, 0, stream>>>(
        w2, qt, (size_t)512 * 512, (size_t)L_ * C_, 512, L_, 512, nullptr, nullptr, nullptr, out, b_out);
}

// Round 3
// 305.046 us; speedup vs baseline: 1.0905x; 1.0359x over previous
//
#include <hip/hip_runtime.h>
#include <hip/hip_bf16.h>

// LinearAttention: B=8, C=512, L=4096, HEADS=8, dim_head=64, hidden=512
// R3: fast transpose_cvt (float4 reads / bf16x4 writes, 2-way-max LDS aliasing);
//     transpose_bf deleted -- GEMM1 q-blocks write q^T directly via LDS-staged
//     epilogue. GEMM structure (global_load_lds 16B + XOR swizzle) unchanged.

typedef __bf16 bf16x8 __attribute__((ext_vector_type(8)));
typedef __bf16 bf16x4 __attribute__((ext_vector_type(4)));
typedef float  f32x4  __attribute__((ext_vector_type(4)));

#define B_  8
#define L_  4096
#define C_  512

#define GLD_LDS16(g, l)                                             \
    __builtin_amdgcn_global_load_lds(                               \
        (const __attribute__((address_space(1))) void*)(g),         \
        (__attribute__((address_space(3))) void*)(l), 16, 0, 0)

// ---------------- small elementwise convert ----------------
__global__ void cvt_bf16(const float* __restrict__ in, __hip_bfloat16* __restrict__ out, int n) {
    int i = blockIdx.x * 256 + threadIdx.x;
    if (i < n) out[i] = __float2bfloat16(in[i]);
}

__global__ void zero_f4(float4* p, int n4) {
    int i = blockIdx.x * 256 + threadIdx.x;
    if (i < n4) p[i] = make_float4(0.f, 0.f, 0.f, 0.f);
}

// ---------------- transpose fp32 [b][C][L] -> bf16 [b][L][C] ----------------
// tile: 64 c-rows x 128 l-cols. Reads: float4, 512B/row segments.
// Writes: bf16x4 (8B/lane), 128B/row segments. LDS stride 132 -> phase-1 b128
// writes 16B-aligned; phase-2 scalar reads bank = (4a+u)%32 -> 2-way max (free).
__global__ __launch_bounds__(256) void transpose_cvt(const float* __restrict__ x,
                                                     __hip_bfloat16* __restrict__ xt) {
    __shared__ float tile[64 * 132];
    int b = blockIdx.z;
    int l0 = blockIdx.x * 128, c0 = blockIdx.y * 64;
    int t = threadIdx.x;
    const float* xp = x + ((size_t)b * C_ + c0) * L_ + l0;
#pragma unroll
    for (int p = 0; p < 8; p++) {
        int i = p * 8 + (t >> 5);
        int j = (t & 31) * 4;
        float4 vv = *(const float4*)(xp + (size_t)i * L_ + j);
        *(float4*)&tile[i * 132 + j] = vv;
    }
    __syncthreads();
    unsigned short* xo = (unsigned short*)xt + ((size_t)b * L_ + l0) * C_ + c0;
#pragma unroll
    for (int qq = 0; qq < 8; qq++) {
        int l = qq * 16 + (t >> 4);
        int cg = (t & 15) * 4;
        bf16x4 ov;
#pragma unroll
        for (int k = 0; k < 4; k++) ov[k] = (__bf16)tile[(cg + k) * 132 + l];
        *(bf16x4*)(xo + (size_t)l * C_ + cg) = ov;
    }
}

// ---------------- main GEMM: C[M][N] = A[M][K] * Bt[N][K]^T ----------------
// A row-major [M][K], Bt row-major [N][K], both bf16, K%32==0, M%128==0, N%128==0.
// Staging: global_load_lds 16B/lane, LDS rows = 64B (32 bf16), 16B-groups
// XOR-swizzled by (row&3) so ds_read_b128 fragments alias only 2-way.
// MODE 1: M=1536 split: rows 0-511 -> q written TRANSPOSED to qt[b][L][512];
//         rows 512-1023 -> k bf16 [b][512][N]; rows 1024-1535 -> v bf16.
// MODE 2: out fp32 [b][M][N] with bias[M]
template <int MODE>
__global__ __launch_bounds__(256) void gemm_bt(
    const __hip_bfloat16* __restrict__ A, const __hip_bfloat16* __restrict__ Bt,
    size_t strideA, size_t strideB, int M, int N, int K,
    __hip_bfloat16* __restrict__ qt, __hip_bfloat16* __restrict__ kb,
    __hip_bfloat16* __restrict__ vb,
    float* __restrict__ outb, const float* __restrict__ bias) {
    __shared__ alignas(16) unsigned short As[128 * 32];  // 8 KiB, rows 64B, swizzled
    __shared__ alignas(16) unsigned short Bs[128 * 32];

    int b = blockIdx.z;
    int m0 = blockIdx.y * 128, n0 = blockIdx.x * 128;
    const __hip_bfloat16* Ab = A + strideA * (size_t)b;
    const __hip_bfloat16* Bb = Bt + strideB * (size_t)b;

    int t = threadIdx.x;
    int lane = t & 63, wv = t >> 6;
    int l16 = lane & 15, q4 = lane >> 4;
    int wr = (wv >> 1) * 64, wc = (wv & 1) * 64;  // wave quadrant of 128x128

    // staging lane mapping: 16 rows/chunk, lane -> (row = lane>>2, kgroup = lane&3)
    int srow = lane >> 2;
    int skg  = lane & 3;
    int kc   = ((skg ^ (srow & 3)) * 8);  // swizzled k-column (elements)

    const __hip_bfloat16* gA0 = Ab + (size_t)(m0 + wv * 32 + srow) * K + kc;
    const __hip_bfloat16* gA1 = gA0 + (size_t)16 * K;
    const __hip_bfloat16* gB0 = Bb + (size_t)(n0 + wv * 32 + srow) * K + kc;
    const __hip_bfloat16* gB1 = gB0 + (size_t)16 * K;
    unsigned short* lA0 = &As[(wv * 32) * 32];
    unsigned short* lA1 = &As[(wv * 32 + 16) * 32];
    unsigned short* lB0 = &Bs[(wv * 32) * 32];
    unsigned short* lB1 = &Bs[(wv * 32 + 16) * 32];

    // fragment read addresses (swizzle: row&3 == l16&3)
    int fsw = (q4 ^ (l16 & 3)) * 8;

    f32x4 acc[4][4] = {};

    for (int k0 = 0; k0 < K; k0 += 32) {
        __syncthreads();  // previous iter's ds_reads done before overwrite
        GLD_LDS16(gA0 + k0, lA0);
        GLD_LDS16(gA1 + k0, lA1);
        GLD_LDS16(gB0 + k0, lB0);
        GLD_LDS16(gB1 + k0, lB1);
        __syncthreads();  // vmcnt drained + all waves' data visible

        bf16x8 af[4], bfr[4];
#pragma unroll
        for (int i = 0; i < 4; i++) {
            af[i]  = *(const bf16x8*)&As[(wr + i * 16 + l16) * 32 + fsw];
            bfr[i] = *(const bf16x8*)&Bs[(wc + i * 16 + l16) * 32 + fsw];
        }
#pragma unroll
        for (int i = 0; i < 4; i++)
#pragma unroll
            for (int j = 0; j < 4; j++)
                acc[i][j] = __builtin_amdgcn_mfma_f32_16x16x32_bf16(af[i], bfr[j], acc[i][j], 0, 0, 0);
    }

    // epilogue: D row = quad*4 + reg, col = lane&15  (m89-verified C/D layout)
    if (MODE == 1 && m0 < 512) {
        // q part: stage tile bf16-transposed in LDS, write qt[b][n][m] coalesced.
        __shared__ alignas(16) unsigned short tbuf[128 * 136];  // [col(l)][row(c')], pad->16B-aligned rows
#pragma unroll
        for (int i = 0; i < 4; i++)
#pragma unroll
            for (int j = 0; j < 4; j++) {
                bf16x4 pk;
#pragma unroll
                for (int r = 0; r < 4; r++) pk[r] = (__bf16)acc[i][j][r];
                *(bf16x4*)&tbuf[(wc + j * 16 + l16) * 136 + (wr + i * 16 + q4 * 4)] = pk;
            }
        __syncthreads();
        unsigned short* qo = (unsigned short*)qt + ((size_t)b * L_ + n0) * 512 + m0;
        int col = t >> 1, half = (t & 1) * 64;
#pragma unroll
        for (int g = 0; g < 8; g++) {
            uint4 vv = *(const uint4*)&tbuf[col * 136 + half + g * 8];
            *(uint4*)(qo + (size_t)col * 512 + half + g * 8) = vv;
        }
    } else {
#pragma unroll
        for (int i = 0; i < 4; i++)
#pragma unroll
            for (int j = 0; j < 4; j++)
#pragma unroll
                for (int r = 0; r < 4; r++) {
                    int row = m0 + wr + i * 16 + q4 * 4 + r;
                    int col = n0 + wc + j * 16 + l16;
                    float val = acc[i][j][r];
                    if (MODE == 1) {
                        int part = row >> 9, od = row & 511;  // block-uniform part (1=k, 2=v)
                        size_t idx = ((size_t)b * 512 + od) * (size_t)N + col;
                        __hip_bfloat16 cv = __float2bfloat16(val);
                        if (part == 1) kb[idx] = cv;
                        else           vb[idx] = cv;
                    } else {
                        outb[((size_t)b * 512 + row) * (size_t)N + col] = val + bias[row];
                    }
                }
    }
}

// ---------------- softmax over rows of k (bf16 in, bf16 out) ----------------
__global__ __launch_bounds__(256) void softmax_k(const __hip_bfloat16* __restrict__ kin,
                                                 __hip_bfloat16* __restrict__ ks) {
    int row = blockIdx.x;  // 0..4095 = b*512 + h*64 + d
    const unsigned short* kp = (const unsigned short*)kin + (size_t)row * L_;
    __shared__ float buf[L_];
    __shared__ float red[8];
    int t = threadIdx.x, lane = t & 63, wv = t >> 6;
    float m = -1e30f;
    for (int i0 = t * 8; i0 < L_; i0 += 256 * 8) {
        bf16x8 kv = *(const bf16x8*)(kp + i0);
#pragma unroll
        for (int j = 0; j < 8; j++) {
            float x = (float)kv[j];
            buf[i0 + j] = x;
            m = fmaxf(m, x);
        }
    }
    for (int o = 32; o; o >>= 1) m = fmaxf(m, __shfl_xor(m, o, 64));
    if (lane == 0) red[wv] = m;
    __syncthreads();
    m = fmaxf(fmaxf(red[0], red[1]), fmaxf(red[2], red[3]));
    float s = 0.f;
    for (int i = t; i < L_; i += 256) { float e = __expf(buf[i] - m); buf[i] = e; s += e; }
    for (int o = 32; o; o >>= 1) s += __shfl_xor(s, o, 64);
    if (lane == 0) red[4 + wv] = s;
    __syncthreads();
    s = red[4] + red[5] + red[6] + red[7];
    float inv = 1.0f / s;
    unsigned short* op = (unsigned short*)ks + (size_t)row * L_;
    for (int i0 = t * 8; i0 < L_; i0 += 256 * 8) {
        bf16x8 ov;
#pragma unroll
        for (int j = 0; j < 8; j++) ov[j] = (__bf16)(buf[i0 + j] * inv);
        *(bf16x8*)(op + i0) = ov;
    }
}

// ---------------- ctx[b,h,d,e] = sum_n k_s[b,h,d,n]*v[b,h,e,n], split-K x8 ----------------
__global__ __launch_bounds__(256) void ctx_kernel(const __hip_bfloat16* __restrict__ ks,
                                                  const __hip_bfloat16* __restrict__ v,
                                                  float* __restrict__ ctx) {
    int kc = blockIdx.x, h = blockIdx.y, b = blockIdx.z;
    int t = threadIdx.x, lane = t & 63, wv = t >> 6;
    int l16 = lane & 15, q4 = lane >> 4;
    const __hip_bfloat16* ka = ks + ((size_t)b * 512 + h * 64) * L_;
    const __hip_bfloat16* va = v + ((size_t)b * 512 + h * 64) * L_;
    f32x4 acc[4][4] = {};
    int nbase = kc * 512 + wv * 128;
#pragma unroll
    for (int s = 0; s < 4; s++) {
        int n = nbase + s * 32 + q4 * 8;
        bf16x8 af[4], bfr[4];
#pragma unroll
        for (int i = 0; i < 4; i++) {
            af[i]  = *(const bf16x8*)(ka + (size_t)(i * 16 + l16) * L_ + n);
            bfr[i] = *(const bf16x8*)(va + (size_t)(i * 16 + l16) * L_ + n);
        }
#pragma unroll
        for (int i = 0; i < 4; i++)
#pragma unroll
            for (int j = 0; j < 4; j++)
                acc[i][j] = __builtin_amdgcn_mfma_f32_16x16x32_bf16(af[i], bfr[j], acc[i][j], 0, 0, 0);
    }
    __shared__ float cbuf[4096];
    for (int w = 0; w < 4; w++) {
        if (wv == w) {
#pragma unroll
            for (int i = 0; i < 4; i++)
#pragma unroll
                for (int j = 0; j < 4; j++)
#pragma unroll
                    for (int r = 0; r < 4; r++) {
                        int mm = i * 16 + q4 * 4 + r, nn = j * 16 + l16;
                        float pv = acc[i][j][r];
                        if (w == 0) cbuf[mm * 64 + nn] = pv;
                        else        cbuf[mm * 64 + nn] += pv;
                    }
        }
        __syncthreads();
    }
    float* cg = ctx + ((size_t)b * 8 + h) * 4096;
    for (int i = t; i < 4096; i += 256) atomicAdd(&cg[i], cbuf[i]);
}

// ---------------- w2[b][o][h*64+d] = sum_e w_out[o][h*64+e]*ctx[b,h,d,e] ----------------
__global__ __launch_bounds__(256) void w2_kernel(const float* __restrict__ wout,
                                                 const float* __restrict__ ctx,
                                                 __hip_bfloat16* __restrict__ w2) {
    int ob = blockIdx.x, h = blockIdx.y, b = blockIdx.z;
    __shared__ float cT[64 * 65];  // [e][d]
    __shared__ float wT[64 * 65];  // [e][ol]
    int t = threadIdx.x;
    const float* cg = ctx + ((size_t)b * 8 + h) * 4096;
    for (int i = t; i < 4096; i += 256) {
        int d = i >> 6, e = i & 63;
        cT[e * 65 + d] = cg[i];
        wT[e * 65 + d] = wout[(size_t)(ob * 64 + d) * 512 + h * 64 + e];
    }
    __syncthreads();
    int ol = t >> 2;
    int db = (t & 3) * 16;
    for (int dd = 0; dd < 16; dd++) {
        int d = db + dd;
        float s = 0.f;
#pragma unroll
        for (int e = 0; e < 64; e++) s += wT[e * 65 + ol] * cT[e * 65 + d];
        w2[((size_t)b * 512 + ob * 64 + ol) * 512 + h * 64 + d] = __float2bfloat16(s);
    }
}

// ---------------- launch ----------------
extern "C" void kernel_launch(void* const* d_in, const int* in_sizes, int n_in,
                              void* d_out, int out_size, void* d_ws, size_t ws_size,
                              hipStream_t stream) {
    const float* x     = (const float*)d_in[0];
    const float* w_qkv = (const float*)d_in[1];
    const float* w_out = (const float*)d_in[2];
    const float* b_out = (const float*)d_in[3];
    float* out = (float*)d_out;
    char* ws = (char*)d_ws;

    const size_t QKV = (size_t)B_ * 512 * L_;  // elements per q/k/v tensor
    size_t off_xt  = 0;                                  // bf16 [b][L][C]   32 MiB
    size_t off_wq  = off_xt + (size_t)B_ * L_ * C_ * 2;  // bf16 1536x512   1.5 MiB
    size_t off_qt  = off_wq + (size_t)1536 * 512 * 2;    // bf16 [b][L][512] 32 MiB
    size_t off_k   = off_qt + QKV * 2;                   // bf16            32 MiB
    size_t off_ks  = off_k + QKV * 2;                    // bf16            32 MiB
    size_t off_v   = off_ks + QKV * 2;                   // bf16            32 MiB
    size_t off_ctx = off_v + QKV * 2;                    // fp32 8*8*64*64   1 MiB
    size_t off_w2  = off_ctx + (size_t)B_ * 8 * 64 * 64 * 4;  // bf16 8*512*512  4 MiB

    __hip_bfloat16* xt  = (__hip_bfloat16*)(ws + off_xt);
    __hip_bfloat16* wq  = (__hip_bfloat16*)(ws + off_wq);
    __hip_bfloat16* qt  = (__hip_bfloat16*)(ws + off_qt);
    __hip_bfloat16* kb  = (__hip_bfloat16*)(ws + off_k);
    __hip_bfloat16* ksb = (__hip_bfloat16*)(ws + off_ks);
    __hip_bfloat16* vb  = (__hip_bfloat16*)(ws + off_v);
    float*          ctx = (float*)(ws + off_ctx);
    __hip_bfloat16* w2  = (__hip_bfloat16*)(ws + off_w2);

    cvt_bf16<<<(1536 * 512 + 255) / 256, 256, 0, stream>>>(w_qkv, wq, 1536 * 512);
    transpose_cvt<<<dim3(L_ / 128, C_ / 64, B_), 256, 0, stream>>>(x, xt);
    zero_f4<<<(B_ * 8 * 64 * 64 / 4 + 255) / 256, 256, 0, stream>>>((float4*)ctx, B_ * 8 * 64 * 64 / 4);

    gemm_bt<1><<<dim3(L_ / 128, 1536 / 128, B_), 256, 0, stream>>>(
        wq, xt, 0, (size_t)L_ * C_, 1536, L_, 512, qt, kb, vb, nullptr, nullptr);

    softmax_k<<<B_ * 512, 256, 0, stream>>>(kb, ksb);
    ctx_kernel<<<dim3(8, 8, B_), 256, 0, stream>>>(ksb, vb, ctx);
    w2_kernel<<<dim3(8, 8, B_), 256, 0, stream>>>(w_out, ctx, w2);

    gemm_bt<2><<<dim3(L_ / 128, 512 / 128, B_), 256, 0, stream>>>(
        w2, qt, (size_t)512 * 512, (size_t)L_ * C_, 512, L_, 512, nullptr, nullptr, nullptr, out, b_out);
}

// Round 4
// 281.307 us; speedup vs baseline: 1.1826x; 1.0844x over previous
//
#include <hip/hip_runtime.h>
#include <hip/hip_bf16.h>

// LinearAttention: B=8, C=512, L=4096, HEADS=8, dim_head=64, hidden=512
// R4: q eliminated algebraically: out = (w2 @ Wq) @ x.
//   GEMM1 computes only k,v (M=1024, clean epilogue, 16KB LDS).
//   GEMM3: W3[b] = w2[b] @ Wq (via WqT), GEMM2: out = W3[b] @ x (uses xt).
//   prep kernel fuses w_kv cvt + WqT transpose + ctx zeroing.

typedef __bf16 bf16x8 __attribute__((ext_vector_type(8)));
typedef __bf16 bf16x4 __attribute__((ext_vector_type(4)));
typedef float  f32x4  __attribute__((ext_vector_type(4)));

#define B_  8
#define L_  4096
#define C_  512

#define GLD_LDS16(g, l)                                             \
    __builtin_amdgcn_global_load_lds(                               \
        (const __attribute__((address_space(1))) void*)(g),         \
        (__attribute__((address_space(3))) void*)(l), 16, 0, 0)

// ---------------- prep: cvt w_qkv kv-part -> bf16; WqT bf16; zero ctx ----------------
__global__ __launch_bounds__(256) void prep(const float* __restrict__ wkv_f,
                                            __hip_bfloat16* __restrict__ wkv_b,
                                            __hip_bfloat16* __restrict__ wqT,
                                            float* __restrict__ ctx) {
    int blk = blockIdx.x;
    if (blk < 2048) {
        int i = blk * 256 + threadIdx.x;  // 1024*512 elements (rows 512..1535)
        wkv_b[i] = __float2bfloat16(wkv_f[512 * 512 + i]);
    } else if (blk < 2048 + 256) {
        // transpose q-part (rows 0..511): wqT[c][c'] = w_qkv[c'][c]
        int tb = blk - 2048;
        int r0 = (tb >> 4) * 32, c0 = (tb & 15) * 32;
        __shared__ float tile[32][33];
        int tx = threadIdx.x & 31, ty = threadIdx.x >> 5;
        for (int r = 0; r < 32; r += 8)
            tile[ty + r][tx] = wkv_f[(size_t)(r0 + ty + r) * 512 + c0 + tx];
        __syncthreads();
        for (int r = 0; r < 32; r += 8)
            wqT[(size_t)(c0 + ty + r) * 512 + r0 + tx] = __float2bfloat16(tile[tx][ty + r]);
    } else {
        int i = (blk - 2304) * 256 + threadIdx.x;  // 262144 floats
        ctx[i] = 0.f;
    }
}

// ---------------- transpose fp32 [b][C][L] -> bf16 [b][L][C] ----------------
__global__ __launch_bounds__(256) void transpose_cvt(const float* __restrict__ x,
                                                     __hip_bfloat16* __restrict__ xt) {
    __shared__ float tile[64 * 132];
    int b = blockIdx.z;
    int l0 = blockIdx.x * 128, c0 = blockIdx.y * 64;
    int t = threadIdx.x;
    const float* xp = x + ((size_t)b * C_ + c0) * L_ + l0;
#pragma unroll
    for (int p = 0; p < 8; p++) {
        int i = p * 8 + (t >> 5);
        int j = (t & 31) * 4;
        float4 vv = *(const float4*)(xp + (size_t)i * L_ + j);
        *(float4*)&tile[i * 132 + j] = vv;
    }
    __syncthreads();
    unsigned short* xo = (unsigned short*)xt + ((size_t)b * L_ + l0) * C_ + c0;
#pragma unroll
    for (int qq = 0; qq < 8; qq++) {
        int l = qq * 16 + (t >> 4);
        int cg = (t & 15) * 4;
        bf16x4 ov;
#pragma unroll
        for (int k = 0; k < 4; k++) ov[k] = (__bf16)tile[(cg + k) * 132 + l];
        *(bf16x4*)(xo + (size_t)l * C_ + cg) = ov;
    }
}

// ---------------- main GEMM: C[M][N] = A[M][K] * Bt[N][K]^T ----------------
// Staging: global_load_lds 16B/lane, LDS rows 64B, XOR-swizzled 16B groups.
// MODE 1: M=1024, rows 0-511 -> kb bf16 [b][512][N], rows 512-1023 -> vb bf16
// MODE 2: out fp32 [b][M][N] + bias[M]
// MODE 3: out bf16 [b][M][N]
template <int MODE>
__global__ __launch_bounds__(256) void gemm_bt(
    const __hip_bfloat16* __restrict__ A, const __hip_bfloat16* __restrict__ Bt,
    size_t strideA, size_t strideB, int M, int N, int K,
    __hip_bfloat16* __restrict__ kb, __hip_bfloat16* __restrict__ vb,
    __hip_bfloat16* __restrict__ obf,
    float* __restrict__ outb, const float* __restrict__ bias) {
    __shared__ alignas(16) unsigned short As[128 * 32];  // 8 KiB
    __shared__ alignas(16) unsigned short Bs[128 * 32];

    int b = blockIdx.z;
    int m0 = blockIdx.y * 128, n0 = blockIdx.x * 128;
    const __hip_bfloat16* Ab = A + strideA * (size_t)b;
    const __hip_bfloat16* Bb = Bt + strideB * (size_t)b;

    int t = threadIdx.x;
    int lane = t & 63, wv = t >> 6;
    int l16 = lane & 15, q4 = lane >> 4;
    int wr = (wv >> 1) * 64, wc = (wv & 1) * 64;

    int srow = lane >> 2;
    int skg  = lane & 3;
    int kc   = ((skg ^ (srow & 3)) * 8);

    const __hip_bfloat16* gA0 = Ab + (size_t)(m0 + wv * 32 + srow) * K + kc;
    const __hip_bfloat16* gA1 = gA0 + (size_t)16 * K;
    const __hip_bfloat16* gB0 = Bb + (size_t)(n0 + wv * 32 + srow) * K + kc;
    const __hip_bfloat16* gB1 = gB0 + (size_t)16 * K;
    unsigned short* lA0 = &As[(wv * 32) * 32];
    unsigned short* lA1 = &As[(wv * 32 + 16) * 32];
    unsigned short* lB0 = &Bs[(wv * 32) * 32];
    unsigned short* lB1 = &Bs[(wv * 32 + 16) * 32];

    int fsw = (q4 ^ (l16 & 3)) * 8;

    f32x4 acc[4][4] = {};

    for (int k0 = 0; k0 < K; k0 += 32) {
        __syncthreads();
        GLD_LDS16(gA0 + k0, lA0);
        GLD_LDS16(gA1 + k0, lA1);
        GLD_LDS16(gB0 + k0, lB0);
        GLD_LDS16(gB1 + k0, lB1);
        __syncthreads();

        bf16x8 af[4], bfr[4];
#pragma unroll
        for (int i = 0; i < 4; i++) {
            af[i]  = *(const bf16x8*)&As[(wr + i * 16 + l16) * 32 + fsw];
            bfr[i] = *(const bf16x8*)&Bs[(wc + i * 16 + l16) * 32 + fsw];
        }
#pragma unroll
        for (int i = 0; i < 4; i++)
#pragma unroll
            for (int j = 0; j < 4; j++)
                acc[i][j] = __builtin_amdgcn_mfma_f32_16x16x32_bf16(af[i], bfr[j], acc[i][j], 0, 0, 0);
    }

    // epilogue: D row = quad*4 + reg, col = lane&15
#pragma unroll
    for (int i = 0; i < 4; i++)
#pragma unroll
        for (int j = 0; j < 4; j++)
#pragma unroll
            for (int r = 0; r < 4; r++) {
                int row = m0 + wr + i * 16 + q4 * 4 + r;
                int col = n0 + wc + j * 16 + l16;
                float val = acc[i][j][r];
                if (MODE == 1) {
                    int part = row >> 9, od = row & 511;  // 0=k, 1=v (block-uniform)
                    size_t idx = ((size_t)b * 512 + od) * (size_t)N + col;
                    __hip_bfloat16 cv = __float2bfloat16(val);
                    if (part == 0) kb[idx] = cv;
                    else           vb[idx] = cv;
                } else if (MODE == 3) {
                    obf[((size_t)b * 512 + row) * (size_t)N + col] = __float2bfloat16(val);
                } else {
                    outb[((size_t)b * 512 + row) * (size_t)N + col] = val + bias[row];
                }
            }
}

// ---------------- softmax over rows of k (bf16 in, bf16 out) ----------------
__global__ __launch_bounds__(256) void softmax_k(const __hip_bfloat16* __restrict__ kin,
                                                 __hip_bfloat16* __restrict__ ks) {
    int row = blockIdx.x;
    const unsigned short* kp = (const unsigned short*)kin + (size_t)row * L_;
    __shared__ float buf[L_];
    __shared__ float red[8];
    int t = threadIdx.x, lane = t & 63, wv = t >> 6;
    float m = -1e30f;
    for (int i0 = t * 8; i0 < L_; i0 += 256 * 8) {
        bf16x8 kv = *(const bf16x8*)(kp + i0);
#pragma unroll
        for (int j = 0; j < 8; j++) {
            float x = (float)kv[j];
            buf[i0 + j] = x;
            m = fmaxf(m, x);
        }
    }
    for (int o = 32; o; o >>= 1) m = fmaxf(m, __shfl_xor(m, o, 64));
    if (lane == 0) red[wv] = m;
    __syncthreads();
    m = fmaxf(fmaxf(red[0], red[1]), fmaxf(red[2], red[3]));
    float s = 0.f;
    for (int i = t; i < L_; i += 256) { float e = __expf(buf[i] - m); buf[i] = e; s += e; }
    for (int o = 32; o; o >>= 1) s += __shfl_xor(s, o, 64);
    if (lane == 0) red[4 + wv] = s;
    __syncthreads();
    s = red[4] + red[5] + red[6] + red[7];
    float inv = 1.0f / s;
    unsigned short* op = (unsigned short*)ks + (size_t)row * L_;
    for (int i0 = t * 8; i0 < L_; i0 += 256 * 8) {
        bf16x8 ov;
#pragma unroll
        for (int j = 0; j < 8; j++) ov[j] = (__bf16)(buf[i0 + j] * inv);
        *(bf16x8*)(op + i0) = ov;
    }
}

// ---------------- ctx[b,h,d,e] = sum_n k_s[b,h,d,n]*v[b,h,e,n], split-K x8 ----------------
__global__ __launch_bounds__(256) void ctx_kernel(const __hip_bfloat16* __restrict__ ks,
                                                  const __hip_bfloat16* __restrict__ v,
                                                  float* __restrict__ ctx) {
    int kc = blockIdx.x, h = blockIdx.y, b = blockIdx.z;
    int t = threadIdx.x, lane = t & 63, wv = t >> 6;
    int l16 = lane & 15, q4 = lane >> 4;
    const __hip_bfloat16* ka = ks + ((size_t)b * 512 + h * 64) * L_;
    const __hip_bfloat16* va = v + ((size_t)b * 512 + h * 64) * L_;
    f32x4 acc[4][4] = {};
    int nbase = kc * 512 + wv * 128;
#pragma unroll
    for (int s = 0; s < 4; s++) {
        int n = nbase + s * 32 + q4 * 8;
        bf16x8 af[4], bfr[4];
#pragma unroll
        for (int i = 0; i < 4; i++) {
            af[i]  = *(const bf16x8*)(ka + (size_t)(i * 16 + l16) * L_ + n);
            bfr[i] = *(const bf16x8*)(va + (size_t)(i * 16 + l16) * L_ + n);
        }
#pragma unroll
        for (int i = 0; i < 4; i++)
#pragma unroll
            for (int j = 0; j < 4; j++)
                acc[i][j] = __builtin_amdgcn_mfma_f32_16x16x32_bf16(af[i], bfr[j], acc[i][j], 0, 0, 0);
    }
    __shared__ float cbuf[4096];
    for (int w = 0; w < 4; w++) {
        if (wv == w) {
#pragma unroll
            for (int i = 0; i < 4; i++)
#pragma unroll
                for (int j = 0; j < 4; j++)
#pragma unroll
                    for (int r = 0; r < 4; r++) {
                        int mm = i * 16 + q4 * 4 + r, nn = j * 16 + l16;
                        float pv = acc[i][j][r];
                        if (w == 0) cbuf[mm * 64 + nn] = pv;
                        else        cbuf[mm * 64 + nn] += pv;
                    }
        }
        __syncthreads();
    }
    float* cg = ctx + ((size_t)b * 8 + h) * 4096;
    for (int i = t; i < 4096; i += 256) atomicAdd(&cg[i], cbuf[i]);
}

// ---------------- w2[b][o][h*64+d] = sum_e w_out[o][h*64+e]*ctx[b,h,d,e] ----------------
__global__ __launch_bounds__(256) void w2_kernel(const float* __restrict__ wout,
                                                 const float* __restrict__ ctx,
                                                 __hip_bfloat16* __restrict__ w2) {
    int ob = blockIdx.x, h = blockIdx.y, b = blockIdx.z;
    __shared__ float cT[64 * 65];  // [e][d]
    __shared__ float wT[64 * 65];  // [e][ol]
    int t = threadIdx.x;
    const float* cg = ctx + ((size_t)b * 8 + h) * 4096;
    for (int i = t; i < 4096; i += 256) {
        int d = i >> 6, e = i & 63;
        cT[e * 65 + d] = cg[i];
        wT[e * 65 + d] = wout[(size_t)(ob * 64 + d) * 512 + h * 64 + e];
    }
    __syncthreads();
    int ol = t >> 2;
    int db = (t & 3) * 16;
    for (int dd = 0; dd < 16; dd++) {
        int d = db + dd;
        float s = 0.f;
#pragma unroll
        for (int e = 0; e < 64; e++) s += wT[e * 65 + ol] * cT[e * 65 + d];
        w2[((size_t)b * 512 + ob * 64 + ol) * 512 + h * 64 + d] = __float2bfloat16(s);
    }
}

// ---------------- launch ----------------
extern "C" void kernel_launch(void* const* d_in, const int* in_sizes, int n_in,
                              void* d_out, int out_size, void* d_ws, size_t ws_size,
                              hipStream_t stream) {
    const float* x     = (const float*)d_in[0];
    const float* w_qkv = (const float*)d_in[1];
    const float* w_out = (const float*)d_in[2];
    const float* b_out = (const float*)d_in[3];
    float* out = (float*)d_out;
    char* ws = (char*)d_ws;

    const size_t QKV = (size_t)B_ * 512 * L_;
    size_t off_xt  = 0;                                   // bf16 [b][L][C]   32 MiB
    size_t off_wkv = off_xt + (size_t)B_ * L_ * C_ * 2;   // bf16 1024x512     1 MiB
    size_t off_wqT = off_wkv + (size_t)1024 * 512 * 2;    // bf16 512x512    0.5 MiB
    size_t off_k   = off_wqT + (size_t)512 * 512 * 2;     // bf16             32 MiB
    size_t off_ks  = off_k + QKV * 2;                     // bf16             32 MiB
    size_t off_v   = off_ks + QKV * 2;                    // bf16             32 MiB
    size_t off_ctx = off_v + QKV * 2;                     // fp32              1 MiB
    size_t off_w2  = off_ctx + (size_t)B_ * 8 * 64 * 64 * 4;   // bf16         4 MiB
    size_t off_w3  = off_w2 + (size_t)B_ * 512 * 512 * 2;      // bf16         4 MiB

    __hip_bfloat16* xt   = (__hip_bfloat16*)(ws + off_xt);
    __hip_bfloat16* wkvb = (__hip_bfloat16*)(ws + off_wkv);
    __hip_bfloat16* wqT  = (__hip_bfloat16*)(ws + off_wqT);
    __hip_bfloat16* kb   = (__hip_bfloat16*)(ws + off_k);
    __hip_bfloat16* ksb  = (__hip_bfloat16*)(ws + off_ks);
    __hip_bfloat16* vb   = (__hip_bfloat16*)(ws + off_v);
    float*          ctx  = (float*)(ws + off_ctx);
    __hip_bfloat16* w2   = (__hip_bfloat16*)(ws + off_w2);
    __hip_bfloat16* W3   = (__hip_bfloat16*)(ws + off_w3);

    prep<<<3328, 256, 0, stream>>>(w_qkv, wkvb, wqT, ctx);
    transpose_cvt<<<dim3(L_ / 128, C_ / 64, B_), 256, 0, stream>>>(x, xt);

    // k,v = Wkv @ x   (M=1024, N=4096, K=512 per batch)
    gemm_bt<1><<<dim3(L_ / 128, 1024 / 128, B_), 256, 0, stream>>>(
        wkvb, xt, 0, (size_t)L_ * C_, 1024, L_, 512, kb, vb, nullptr, nullptr, nullptr);

    softmax_k<<<B_ * 512, 256, 0, stream>>>(kb, ksb);
    ctx_kernel<<<dim3(8, 8, B_), 256, 0, stream>>>(ksb, vb, ctx);
    w2_kernel<<<dim3(8, 8, B_), 256, 0, stream>>>(w_out, ctx, w2);

    // W3[b] = w2[b] @ Wq   (M=512, N=512, K=512)
    gemm_bt<3><<<dim3(512 / 128, 512 / 128, B_), 256, 0, stream>>>(
        w2, wqT, (size_t)512 * 512, 0, 512, 512, 512, nullptr, nullptr, W3, nullptr, nullptr);

    // out = W3[b] @ x[b] + b_out   (M=512, N=4096, K=512)
    gemm_bt<2><<<dim3(L_ / 128, 512 / 128, B_), 256, 0, stream>>>(
        W3, xt, (size_t)512 * 512, (size_t)L_ * C_, 512, L_, 512, nullptr, nullptr, nullptr, out, b_out);
}

// Round 5
// 261.139 us; speedup vs baseline: 1.2739x; 1.0772x over previous
//
#include <hip/hip_runtime.h>
#include <hip/hip_bf16.h>

// LinearAttention: B=8, C=512, L=4096, HEADS=8, dim_head=64, hidden=512
// R5: BK=64 GEMM (128B LDS rows, 3-bit XOR swizzle -> conflict-free b128 reads,
//     half the barrier drains); softmax pass replaced by rowstat + exp-on-the-fly
//     in ctx_kernel; prep+transpose merged into one dispatch.
// Pipeline: prep_all; kv=GEMM1(wkv,xt); rowstat(k); ctx(k,stats,v); w2; W3=w2@Wq; out=W3@x.

typedef __bf16 bf16x8 __attribute__((ext_vector_type(8)));
typedef __bf16 bf16x4 __attribute__((ext_vector_type(4)));
typedef float  f32x4  __attribute__((ext_vector_type(4)));

#define B_  8
#define L_  4096
#define C_  512

#define GLD_LDS16(g, l)                                             \
    __builtin_amdgcn_global_load_lds(                               \
        (const __attribute__((address_space(1))) void*)(g),         \
        (__attribute__((address_space(3))) void*)(l), 16, 0, 0)

// ---------------- prep_all: x-transpose+cvt | wkv cvt | WqT | ctx zero ----------------
__global__ __launch_bounds__(256) void prep_all(const float* __restrict__ x,
                                                __hip_bfloat16* __restrict__ xt,
                                                const float* __restrict__ wqkv_f,
                                                __hip_bfloat16* __restrict__ wkv_b,
                                                __hip_bfloat16* __restrict__ wqT,
                                                float* __restrict__ ctx) {
    __shared__ float tile[64 * 132];
    int blk = blockIdx.x;
    int t = threadIdx.x;
    if (blk < 2048) {
        // transpose fp32 x[b][C][L] -> bf16 xt[b][L][C]; 64c x 128l tile
        int b = blk >> 8, rem = blk & 255;
        int l0 = (rem & 31) * 128, c0 = (rem >> 5) * 64;
        const float* xp = x + ((size_t)b * C_ + c0) * L_ + l0;
#pragma unroll
        for (int p = 0; p < 8; p++) {
            int i = p * 8 + (t >> 5);
            int j = (t & 31) * 4;
            float4 vv = *(const float4*)(xp + (size_t)i * L_ + j);
            *(float4*)&tile[i * 132 + j] = vv;
        }
        __syncthreads();
        unsigned short* xo = (unsigned short*)xt + ((size_t)b * L_ + l0) * C_ + c0;
#pragma unroll
        for (int qq = 0; qq < 8; qq++) {
            int l = qq * 16 + (t >> 4);
            int cg = (t & 15) * 4;
            bf16x4 ov;
#pragma unroll
            for (int k = 0; k < 4; k++) ov[k] = (__bf16)tile[(cg + k) * 132 + l];
            *(bf16x4*)(xo + (size_t)l * C_ + cg) = ov;
        }
    } else if (blk < 4096) {
        int i = (blk - 2048) * 256 + t;  // 1024*512 elements (w_qkv rows 512..1535)
        wkv_b[i] = __float2bfloat16(wqkv_f[512 * 512 + i]);
    } else if (blk < 4352) {
        // wqT[c][c'] = w_qkv[c'][c] (q-part rows 0..511), bf16
        int tb = blk - 4096;
        int r0 = (tb >> 4) * 32, c0 = (tb & 15) * 32;
        int tx = t & 31, ty = t >> 5;
        for (int r = 0; r < 32; r += 8)
            tile[(ty + r) * 33 + tx] = wqkv_f[(size_t)(r0 + ty + r) * 512 + c0 + tx];
        __syncthreads();
        for (int r = 0; r < 32; r += 8)
            wqT[(size_t)(c0 + ty + r) * 512 + r0 + tx] = __float2bfloat16(tile[tx * 33 + ty + r]);
    } else {
        int i = (blk - 4352) * 256 + t;  // 262144 floats
        ctx[i] = 0.f;
    }
}

// ---------------- main GEMM: C[M][N] = A[M][K] * Bt[N][K]^T, BK=64 ----------------
// A row-major [M][K], Bt row-major [N][K], bf16, K%64==0, M%128==0, N%128==0.
// LDS rows 128B (64 el); 16B group g of row r holds global k-group (g ^ (r&7)).
// Staging: global_load_lds 16B/lane, lane n -> row n>>3, group n&7.
// Fragment reads: group (ks*4+q4)^(l16&7) -> every 8-lane phase covers all 32 banks.
// MODE 1: M=1024: rows 0-511 -> kb bf16 [b][512][N], 512-1023 -> vb
// MODE 2: out fp32 [b][M][N] + bias[M];  MODE 3: out bf16
template <int MODE>
__global__ __launch_bounds__(256) void gemm_bt(
    const __hip_bfloat16* __restrict__ A, const __hip_bfloat16* __restrict__ Bt,
    size_t strideA, size_t strideB, int M, int N, int K,
    __hip_bfloat16* __restrict__ kb, __hip_bfloat16* __restrict__ vb,
    __hip_bfloat16* __restrict__ obf,
    float* __restrict__ outb, const float* __restrict__ bias) {
    __shared__ alignas(16) unsigned short As[128 * 64];  // 16 KiB
    __shared__ alignas(16) unsigned short Bs[128 * 64];

    int b = blockIdx.z;
    int m0 = blockIdx.y * 128, n0 = blockIdx.x * 128;
    const __hip_bfloat16* Ab = A + strideA * (size_t)b;
    const __hip_bfloat16* Bb = Bt + strideB * (size_t)b;

    int t = threadIdx.x;
    int lane = t & 63, wv = t >> 6;
    int l16 = lane & 15, q4 = lane >> 4;
    int wr = (wv >> 1) * 64, wc = (wv & 1) * 64;

    // staging: 8 rows per GLD inst; lane -> (srow = lane>>3, group = lane&7)
    int srow = lane >> 3;
    int swz  = ((lane & 7) ^ srow) * 8;  // swizzled k-column (elements)

    const __hip_bfloat16* gA[4];
    const __hip_bfloat16* gB[4];
    unsigned short* lA[4];
    unsigned short* lB[4];
#pragma unroll
    for (int c = 0; c < 4; c++) {
        int r = wv * 32 + c * 8;
        gA[c] = Ab + (size_t)(m0 + r + srow) * K + swz;
        gB[c] = Bb + (size_t)(n0 + r + srow) * K + swz;
        lA[c] = &As[r * 64];
        lB[c] = &Bs[r * 64];
    }

    int gsel0 = ((q4) ^ (l16 & 7)) * 8;
    int gsel1 = ((4 + q4) ^ (l16 & 7)) * 8;
    int rA = (wr + l16) * 64;
    int rB = (wc + l16) * 64;

    f32x4 acc[4][4] = {};

    for (int k0 = 0; k0 < K; k0 += 64) {
        __syncthreads();  // previous iter's ds_reads done before overwrite
#pragma unroll
        for (int c = 0; c < 4; c++) {
            GLD_LDS16(gA[c] + k0, lA[c]);
            GLD_LDS16(gB[c] + k0, lB[c]);
        }
        __syncthreads();  // staging visible to all waves

        bf16x8 af[4], bfr[4];
        // ks = 0 (k-columns 0..31)
#pragma unroll
        for (int i = 0; i < 4; i++) {
            af[i]  = *(const bf16x8*)&As[rA + i * 1024 + gsel0];
            bfr[i] = *(const bf16x8*)&Bs[rB + i * 1024 + gsel0];
        }
#pragma unroll
        for (int i = 0; i < 4; i++)
#pragma unroll
            for (int j = 0; j < 4; j++)
                acc[i][j] = __builtin_amdgcn_mfma_f32_16x16x32_bf16(af[i], bfr[j], acc[i][j], 0, 0, 0);
        // ks = 1 (k-columns 32..63)
#pragma unroll
        for (int i = 0; i < 4; i++) {
            af[i]  = *(const bf16x8*)&As[rA + i * 1024 + gsel1];
            bfr[i] = *(const bf16x8*)&Bs[rB + i * 1024 + gsel1];
        }
#pragma unroll
        for (int i = 0; i < 4; i++)
#pragma unroll
            for (int j = 0; j < 4; j++)
                acc[i][j] = __builtin_amdgcn_mfma_f32_16x16x32_bf16(af[i], bfr[j], acc[i][j], 0, 0, 0);
    }

    // epilogue: D row = quad*4 + reg, col = lane&15
#pragma unroll
    for (int i = 0; i < 4; i++)
#pragma unroll
        for (int j = 0; j < 4; j++)
#pragma unroll
            for (int r = 0; r < 4; r++) {
                int row = m0 + wr + i * 16 + q4 * 4 + r;
                int col = n0 + wc + j * 16 + l16;
                float val = acc[i][j][r];
                if (MODE == 1) {
                    int part = row >> 9, od = row & 511;  // 0=k, 1=v (block-uniform)
                    size_t idx = ((size_t)b * 512 + od) * (size_t)N + col;
                    __hip_bfloat16 cv = __float2bfloat16(val);
                    if (part == 0) kb[idx] = cv;
                    else           vb[idx] = cv;
                } else if (MODE == 3) {
                    obf[((size_t)b * 512 + row) * (size_t)N + col] = __float2bfloat16(val);
                } else {
                    outb[((size_t)b * 512 + row) * (size_t)N + col] = val + bias[row];
                }
            }
}

// ---------------- rowstat: per-row max and 1/sum(exp) of k ----------------
__global__ __launch_bounds__(256) void rowstat(const __hip_bfloat16* __restrict__ kin,
                                               float* __restrict__ mrow,
                                               float* __restrict__ isrow) {
    int row = blockIdx.x;  // 0..4095
    const unsigned short* kp = (const unsigned short*)kin + (size_t)row * L_;
    __shared__ float buf[L_];
    __shared__ float red[8];
    int t = threadIdx.x, lane = t & 63, wv = t >> 6;
    float m = -1e30f;
    for (int i0 = t * 8; i0 < L_; i0 += 256 * 8) {
        bf16x8 kv = *(const bf16x8*)(kp + i0);
#pragma unroll
        for (int j = 0; j < 8; j++) {
            float xx = (float)kv[j];
            buf[i0 + j] = xx;
            m = fmaxf(m, xx);
        }
    }
    for (int o = 32; o; o >>= 1) m = fmaxf(m, __shfl_xor(m, o, 64));
    if (lane == 0) red[wv] = m;
    __syncthreads();
    m = fmaxf(fmaxf(red[0], red[1]), fmaxf(red[2], red[3]));
    float s = 0.f;
    for (int i = t; i < L_; i += 256) s += __expf(buf[i] - m);
    for (int o = 32; o; o >>= 1) s += __shfl_xor(s, o, 64);
    if (lane == 0) red[4 + wv] = s;
    __syncthreads();
    if (t == 0) {
        s = red[4] + red[5] + red[6] + red[7];
        mrow[row] = m;
        isrow[row] = 1.0f / s;
    }
}

// ---------------- ctx[b,h,d,e] = sum_n softmax(k)[d,n]*v[e,n], split-K x8 ----------------
__global__ __launch_bounds__(256) void ctx_kernel(const __hip_bfloat16* __restrict__ kraw,
                                                  const float* __restrict__ mrow,
                                                  const float* __restrict__ isrow,
                                                  const __hip_bfloat16* __restrict__ v,
                                                  float* __restrict__ ctx) {
    int kc = blockIdx.x, h = blockIdx.y, b = blockIdx.z;
    int t = threadIdx.x, lane = t & 63, wv = t >> 6;
    int l16 = lane & 15, q4 = lane >> 4;
    const __hip_bfloat16* ka = kraw + ((size_t)b * 512 + h * 64) * L_;
    const __hip_bfloat16* va = v + ((size_t)b * 512 + h * 64) * L_;
    int rbase = b * 512 + h * 64;
    float mr[4], ir[4];
#pragma unroll
    for (int i = 0; i < 4; i++) {
        mr[i] = mrow[rbase + i * 16 + l16];
        ir[i] = isrow[rbase + i * 16 + l16];
    }
    f32x4 acc[4][4] = {};
    int nbase = kc * 512 + wv * 128;
#pragma unroll
    for (int s = 0; s < 4; s++) {
        int n = nbase + s * 32 + q4 * 8;
        bf16x8 af[4], bfr[4];
#pragma unroll
        for (int i = 0; i < 4; i++) {
            bf16x8 kv = *(const bf16x8*)(ka + (size_t)(i * 16 + l16) * L_ + n);
#pragma unroll
            for (int e = 0; e < 8; e++)
                af[i][e] = (__bf16)(__expf((float)kv[e] - mr[i]) * ir[i]);
            bfr[i] = *(const bf16x8*)(va + (size_t)(i * 16 + l16) * L_ + n);
        }
#pragma unroll
        for (int i = 0; i < 4; i++)
#pragma unroll
            for (int j = 0; j < 4; j++)
                acc[i][j] = __builtin_amdgcn_mfma_f32_16x16x32_bf16(af[i], bfr[j], acc[i][j], 0, 0, 0);
    }
    __shared__ float cbuf[4096];
    for (int w = 0; w < 4; w++) {
        if (wv == w) {
#pragma unroll
            for (int i = 0; i < 4; i++)
#pragma unroll
                for (int j = 0; j < 4; j++)
#pragma unroll
                    for (int r = 0; r < 4; r++) {
                        int mm = i * 16 + q4 * 4 + r, nn = j * 16 + l16;
                        float pv = acc[i][j][r];
                        if (w == 0) cbuf[mm * 64 + nn] = pv;
                        else        cbuf[mm * 64 + nn] += pv;
                    }
        }
        __syncthreads();
    }
    float* cg = ctx + ((size_t)b * 8 + h) * 4096;
    for (int i = t; i < 4096; i += 256) atomicAdd(&cg[i], cbuf[i]);
}

// ---------------- w2[b][o][h*64+d] = sum_e w_out[o][h*64+e]*ctx[b,h,d,e] ----------------
__global__ __launch_bounds__(256) void w2_kernel(const float* __restrict__ wout,
                                                 const float* __restrict__ ctx,
                                                 __hip_bfloat16* __restrict__ w2) {
    int ob = blockIdx.x, h = blockIdx.y, b = blockIdx.z;
    __shared__ float cT[64 * 65];  // [e][d]
    __shared__ float wT[64 * 65];  // [e][ol]
    int t = threadIdx.x;
    const float* cg = ctx + ((size_t)b * 8 + h) * 4096;
    for (int i = t; i < 4096; i += 256) {
        int d = i >> 6, e = i & 63;
        cT[e * 65 + d] = cg[i];
        wT[e * 65 + d] = wout[(size_t)(ob * 64 + d) * 512 + h * 64 + e];
    }
    __syncthreads();
    int ol = t >> 2;
    int db = (t & 3) * 16;
    for (int dd = 0; dd < 16; dd++) {
        int d = db + dd;
        float s = 0.f;
#pragma unroll
        for (int e = 0; e < 64; e++) s += wT[e * 65 + ol] * cT[e * 65 + d];
        w2[((size_t)b * 512 + ob * 64 + ol) * 512 + h * 64 + d] = __float2bfloat16(s);
    }
}

// ---------------- launch ----------------
extern "C" void kernel_launch(void* const* d_in, const int* in_sizes, int n_in,
                              void* d_out, int out_size, void* d_ws, size_t ws_size,
                              hipStream_t stream) {
    const float* x     = (const float*)d_in[0];
    const float* w_qkv = (const float*)d_in[1];
    const float* w_out = (const float*)d_in[2];
    const float* b_out = (const float*)d_in[3];
    float* out = (float*)d_out;
    char* ws = (char*)d_ws;

    const size_t QKV = (size_t)B_ * 512 * L_;
    size_t off_xt  = 0;                                   // bf16 [b][L][C]   32 MiB
    size_t off_wkv = off_xt + (size_t)B_ * L_ * C_ * 2;   // bf16 1024x512     1 MiB
    size_t off_wqT = off_wkv + (size_t)1024 * 512 * 2;    // bf16 512x512    0.5 MiB
    size_t off_k   = off_wqT + (size_t)512 * 512 * 2;     // bf16             32 MiB
    size_t off_v   = off_k + QKV * 2;                     // bf16             32 MiB
    size_t off_ms  = off_v + QKV * 2;                     // fp32 4096        16 KiB
    size_t off_is  = off_ms + 4096 * 4;                   // fp32 4096        16 KiB
    size_t off_ctx = off_is + 4096 * 4;                   // fp32              1 MiB
    size_t off_w2  = off_ctx + (size_t)B_ * 8 * 64 * 64 * 4;   // bf16         4 MiB
    size_t off_w3  = off_w2 + (size_t)B_ * 512 * 512 * 2;      // bf16         4 MiB

    __hip_bfloat16* xt   = (__hip_bfloat16*)(ws + off_xt);
    __hip_bfloat16* wkvb = (__hip_bfloat16*)(ws + off_wkv);
    __hip_bfloat16* wqT  = (__hip_bfloat16*)(ws + off_wqT);
    __hip_bfloat16* kb   = (__hip_bfloat16*)(ws + off_k);
    __hip_bfloat16* vb   = (__hip_bfloat16*)(ws + off_v);
    float*          ms   = (float*)(ws + off_ms);
    float*          isv  = (float*)(ws + off_is);
    float*          ctx  = (float*)(ws + off_ctx);
    __hip_bfloat16* w2   = (__hip_bfloat16*)(ws + off_w2);
    __hip_bfloat16* W3   = (__hip_bfloat16*)(ws + off_w3);

    prep_all<<<5376, 256, 0, stream>>>(x, xt, w_qkv, wkvb, wqT, ctx);

    // k,v = Wkv @ x   (M=1024, N=4096, K=512 per batch)
    gemm_bt<1><<<dim3(L_ / 128, 1024 / 128, B_), 256, 0, stream>>>(
        wkvb, xt, 0, (size_t)L_ * C_, 1024, L_, 512, kb, vb, nullptr, nullptr, nullptr);

    rowstat<<<B_ * 512, 256, 0, stream>>>(kb, ms, isv);
    ctx_kernel<<<dim3(8, 8, B_), 256, 0, stream>>>(kb, ms, isv, vb, ctx);
    w2_kernel<<<dim3(8, 8, B_), 256, 0, stream>>>(w_out, ctx, w2);

    // W3[b] = w2[b] @ Wq   (M=512, N=512, K=512)
    gemm_bt<3><<<dim3(512 / 128, 512 / 128, B_), 256, 0, stream>>>(
        w2, wqT, (size_t)512 * 512, 0, 512, 512, 512, nullptr, nullptr, W3, nullptr, nullptr);

    // out = W3[b] @ x[b] + b_out   (M=512, N=4096, K=512)
    gemm_bt<2><<<dim3(L_ / 128, 512 / 128, B_), 256, 0, stream>>>(
        W3, xt, (size_t)512 * 512, (size_t)L_ * C_, 512, L_, 512, nullptr, nullptr, nullptr, out, b_out);
}